// Round 3
// baseline (24969.426 us; speedup 1.0000x reference)
//
#include <hip/hip_runtime.h>
#include <stdint.h>

#define T_LEN 4096
#define E_DIM 256
#define HH 256

typedef unsigned long long u64;
typedef float f32x4 __attribute__((ext_vector_type(4)));

__device__ __forceinline__ float sigmoidf_(float x) {
    // 1/(1+e^-x) with approx rcp (rel err ~1e-7, fine vs 2% score threshold)
    return __builtin_amdgcn_rcpf(1.0f + __expf(-x));
}
// tanh via exp identity; exact saturation at +-1
__device__ __forceinline__ float tanh_fast(float x) {
    float e = __expf(2.0f * x);
    return 1.0f - 2.0f * __builtin_amdgcn_rcpf(e + 1.0f);
}

// DPP-based add of a permuted lane: pure VALU. CTRL: 0xB1 = quad_perm xor1,
// 0x4E = quad_perm xor2, 0x141 = ROW_HALF_MIRROR (l^7), 0x140 = ROW_MIRROR
// (l^15). After the 4-round chain ALL 16 lanes of each 16-row hold the row
// sum (mirrors are valid because values are quad/octet-uniform by then).
template <int CTRL>
__device__ __forceinline__ float dpp_add(float x) {
    int t = __builtin_amdgcn_update_dpp(0, __float_as_int(x), CTRL, 0xF, 0xF, true);
    return x + __int_as_float(t);
}

// ---------------------------------------------------------------------------
// Kernel 1: embedding gather fused with input projection. (unchanged)
// ---------------------------------------------------------------------------
__global__ __launch_bounds__(256) void proj_kernel(
    const int* __restrict__ sent, const float* __restrict__ embed,
    const float* __restrict__ Wih_f, const float* __restrict__ bih_f, const float* __restrict__ bhh_f,
    const float* __restrict__ Wih_b, const float* __restrict__ bih_b, const float* __restrict__ bhh_b,
    float* __restrict__ gates_f, float* __restrict__ gates_b)
{
    __shared__ float4 xt[16][64];   // 16 timesteps x 256 floats
    const int tid = threadIdx.x;
    const int dir = blockIdx.y;
    const int t0  = blockIdx.x * 16;

    const float* Wih = dir ? Wih_b : Wih_f;
    const float* bih = dir ? bih_b : bih_f;
    const float* bhh = dir ? bhh_b : bhh_f;
    float* gates     = dir ? gates_b : gates_f;

    {   // gather 16 embedding rows into LDS (coalesced 16B/lane)
        int row = tid >> 4;
        int c   = tid & 15;
        const float4* src = (const float4*)(embed + (size_t)sent[t0 + row] * E_DIM);
        xt[row][c]      = src[c];
        xt[row][c + 16] = src[c + 16];
        xt[row][c + 32] = src[c + 32];
        xt[row][c + 48] = src[c + 48];
    }
    __syncthreads();

    float acc[4][16];
    #pragma unroll
    for (int ri = 0; ri < 4; ++ri)
        #pragma unroll
        for (int tt = 0; tt < 16; ++tt) acc[ri][tt] = 0.f;

    const float4* wrow0 = (const float4*)(Wih + (size_t)(0 * 256 + tid) * 256);
    const float4* wrow1 = (const float4*)(Wih + (size_t)(1 * 256 + tid) * 256);
    const float4* wrow2 = (const float4*)(Wih + (size_t)(2 * 256 + tid) * 256);
    const float4* wrow3 = (const float4*)(Wih + (size_t)(3 * 256 + tid) * 256);

    for (int k4 = 0; k4 < 64; ++k4) {
        float4 xv[16];
        #pragma unroll
        for (int tt = 0; tt < 16; ++tt) xv[tt] = xt[tt][k4];
        float4 w0 = wrow0[k4], w1 = wrow1[k4], w2 = wrow2[k4], w3 = wrow3[k4];
        #pragma unroll
        for (int tt = 0; tt < 16; ++tt) {
            acc[0][tt] += w0.x*xv[tt].x + w0.y*xv[tt].y + w0.z*xv[tt].z + w0.w*xv[tt].w;
            acc[1][tt] += w1.x*xv[tt].x + w1.y*xv[tt].y + w1.z*xv[tt].z + w1.w*xv[tt].w;
            acc[2][tt] += w2.x*xv[tt].x + w2.y*xv[tt].y + w2.z*xv[tt].z + w2.w*xv[tt].w;
            acc[3][tt] += w3.x*xv[tt].x + w3.y*xv[tt].y + w3.z*xv[tt].z + w3.w*xv[tt].w;
        }
    }

    #pragma unroll
    for (int ri = 0; ri < 4; ++ri) {
        int r = ri * 256 + tid;
        float b = bih[r] + bhh[r];
        #pragma unroll
        for (int tt = 0; tt < 16; ++tt)
            gates[(size_t)(t0 + tt) * 1024 + r] = acc[ri][tt] + b;
    }
}

// ---------------------------------------------------------------------------
// Kernel 2: BiLSTM recurrence. 64 blocks; blockIdx&7 in {0,1} work (dir=xcd).
// 8 blocks/dir x 32 hidden; thread (j=tid>>4, s=tid&15).
// R7: per-thread DIRECT poll. Each thread polls its 16 contiguous msg slots
// (k = s*16..s*16+15) with 8x global_load_dwordx4 sc0 (XCD-L2 scope) into
// registers -> h_lds / ds_read staging hop removed entirely (no LDS in this
// kernel). Producer publishes sc0 (fast, L2) + the old AGENT atomic as a
// mirror; sticky per-thread fallback to the mirror poll keeps correctness
// independent of XCD placement (worst case = R6 behavior, no hang).
// Barrier stays between poll and publish: ABA proof unchanged (remote tag
// t+1 implies remote block passed its poll-barrier, so tag-t was consumed).
// Slot = u64 {lo=val, hi=tag}; an 8B store never tears within a 16B load.
// ---------------------------------------------------------------------------
__global__ __launch_bounds__(512, 1) void lstm_kernel(
    const float* __restrict__ Whh_f, const float* __restrict__ Whh_b,
    const float* __restrict__ gates_f, const float* __restrict__ gates_b,
    const float* __restrict__ h0, const float* __restrict__ c0,
    float* __restrict__ h_out, u64* __restrict__ msg, u64* __restrict__ msgf)
{
    const int xcd  = blockIdx.x & 7;
    const int slot = blockIdx.x >> 3;
    if (xcd > 1) return;               // filler blocks exit
    const int dir = xcd;
    const int g   = slot;              // 0..7, owns hidden [g*32, g*32+32)

    const int tid = threadIdx.x;
    const int jl  = tid >> 4;          // local hidden 0..31
    const int s   = tid & 15;          // k-slice 0..15 (16 floats each)
    const int j   = g * 32 + jl;       // global hidden index

    const float* Whh   = dir ? Whh_b : Whh_f;
    const float* gates = dir ? gates_b : gates_f;

    // weights, plain k-order now (no LDS => no bank rotation needed)
    float w[64];
    #pragma unroll
    for (int gg = 0; gg < 4; ++gg) {
        const float4* row = (const float4*)(Whh + (size_t)(gg * 256 + j) * 256 + s * 16);
        #pragma unroll
        for (int i = 0; i < 4; ++i) {
            float4 v = row[i];
            w[gg * 16 + i * 4 + 0] = v.x;
            w[gg * 16 + i * 4 + 1] = v.y;
            w[gg * 16 + i * 4 + 2] = v.z;
            w[gg * 16 + i * 4 + 3] = v.w;
        }
    }
    // AGPR pin (R6-proven): VALU reads a-regs in place, no refills/remat.
    #pragma unroll
    for (int k = 0; k < 64; ++k)
        asm volatile("" : "+a"(w[k]));

    float c = c0[dir * HH + j];        // carried redundantly in all 16 s-lanes

    // init: zero buf1 (ABA garbage guard in the NEW fast array), fence,
    // then publish h0 with tag 1 into buf0. Same-lane program order +
    // fence => consumers can never see garbage-tagged buf1.
    if (s == 0) {
        float hinit = h0[dir * HH + j];
        u64 p1 = ((u64)1u << 32) | (u64)__float_as_uint(hinit);
        u64* z1f = msgf + (size_t)(1 * 2 + dir) * 256 + j;
        asm volatile("global_store_dwordx2 %0, %1, off sc0"
                     :: "v"((u64)(uintptr_t)z1f), "v"(0ull) : "memory");
        __hip_atomic_store(&msg[(1 * 2 + dir) * 256 + j], 0ull,
                           __ATOMIC_RELAXED, __HIP_MEMORY_SCOPE_AGENT);
        __threadfence();
        u64* f0 = msgf + (size_t)(0 * 2 + dir) * 256 + j;
        asm volatile("global_store_dwordx2 %0, %1, off sc0"
                     :: "v"((u64)(uintptr_t)f0), "v"(p1) : "memory");
        __hip_atomic_store(&msg[(0 * 2 + dir) * 256 + j], p1,
                           __ATOMIC_RELAXED, __HIP_MEMORY_SCOPE_AGENT);
    }

    // gin: all lanes load (same addr within an s-group -> coalescer merges).
    // First load is pre-loop; subsequent loads prefetched one step ahead,
    // issued AFTER the poll so the sweep's vmcnt(0) never couples to HBM.
    const ptrdiff_t dstep = dir ? -1024 : 1024;
    const float* gp = gates + (size_t)(dir ? (T_LEN - 1) : 0) * 1024 + j;
    float gin0 = gp[0], gin1 = gp[256], gin2 = gp[512], gin3 = gp[768];

    const u64 pb0 = (u64)(uintptr_t)(msgf + (size_t)(0 * 2 + dir) * 256 + s * 16);
    const u64 pb1 = (u64)(uintptr_t)(msgf + (size_t)(1 * 2 + dir) * 256 + s * 16);
    const u64* sb0 = msg + (size_t)(0 * 2 + dir) * 256 + s * 16;
    const u64* sb1 = msg + (size_t)(1 * 2 + dir) * 256 + s * 16;

    int fastmode = 1;   // sticky; drops to mirror protocol if sc0 path stale

    for (int t = 0; t < T_LEN; ++t) {
        const int tf = dir ? (T_LEN - 1 - t) : t;
        const unsigned want = (unsigned)(t + 1);

        float hv[16];
        if (fastmode) {
            const u64 pb = (t & 1) ? pb1 : pb0;
            int spins = 0;
            for (;;) {
                f32x4 q0, q1, q2, q3, q4, q5, q6, q7;
                asm volatile(
                    "global_load_dwordx4 %0, %8, off sc0\n\t"
                    "global_load_dwordx4 %1, %8, off offset:16 sc0\n\t"
                    "global_load_dwordx4 %2, %8, off offset:32 sc0\n\t"
                    "global_load_dwordx4 %3, %8, off offset:48 sc0\n\t"
                    "global_load_dwordx4 %4, %8, off offset:64 sc0\n\t"
                    "global_load_dwordx4 %5, %8, off offset:80 sc0\n\t"
                    "global_load_dwordx4 %6, %8, off offset:96 sc0\n\t"
                    "global_load_dwordx4 %7, %8, off offset:112 sc0\n\t"
                    "s_waitcnt vmcnt(0)"
                    : "=&v"(q0), "=&v"(q1), "=&v"(q2), "=&v"(q3),
                      "=&v"(q4), "=&v"(q5), "=&v"(q6), "=&v"(q7)
                    : "v"(pb)
                    : "memory");
                unsigned d;
                d  = (__float_as_uint(q0.y) ^ want) | (__float_as_uint(q0.w) ^ want);
                d |= (__float_as_uint(q1.y) ^ want) | (__float_as_uint(q1.w) ^ want);
                d |= (__float_as_uint(q2.y) ^ want) | (__float_as_uint(q2.w) ^ want);
                d |= (__float_as_uint(q3.y) ^ want) | (__float_as_uint(q3.w) ^ want);
                d |= (__float_as_uint(q4.y) ^ want) | (__float_as_uint(q4.w) ^ want);
                d |= (__float_as_uint(q5.y) ^ want) | (__float_as_uint(q5.w) ^ want);
                d |= (__float_as_uint(q6.y) ^ want) | (__float_as_uint(q6.w) ^ want);
                d |= (__float_as_uint(q7.y) ^ want) | (__float_as_uint(q7.w) ^ want);
                if (d == 0) {
                    hv[0]  = q0.x; hv[1]  = q0.z; hv[2]  = q1.x; hv[3]  = q1.z;
                    hv[4]  = q2.x; hv[5]  = q2.z; hv[6]  = q3.x; hv[7]  = q3.z;
                    hv[8]  = q4.x; hv[9]  = q4.z; hv[10] = q5.x; hv[11] = q5.z;
                    hv[12] = q6.x; hv[13] = q6.z; hv[14] = q7.x; hv[15] = q7.z;
                    break;
                }
                if (++spins > 1024) { fastmode = 0; break; }
            }
        }
        if (!fastmode) {
            // placement-robust mirror poll (R6 protocol). Unrolled so hv
            // stays statically indexed (rule #20: no scratch).
            const u64* sb = (t & 1) ? sb1 : sb0;
            #pragma unroll
            for (int i = 0; i < 16; ++i) {
                u64 m;
                do {
                    m = __hip_atomic_load(&sb[i], __ATOMIC_RELAXED, __HIP_MEMORY_SCOPE_AGENT);
                } while ((unsigned)(m >> 32) != want);
                hv[i] = __uint_as_float((unsigned)m);
            }
        }
        __syncthreads();   // the ONLY barrier per step (carries ABA proof)

        // prefetch NEXT step's gate inputs (hides HBM under dot+act+next poll)
        const float* gn = gp + dstep;
        float ng0 = gn[0], ng1 = gn[256], ng2 = gn[512], ng3 = gn[768];

        // 4-gate partial dot over this thread's 16-k slice, straight from regs
        float p0 = 0.f, p1 = 0.f, p2 = 0.f, p3 = 0.f;
        #pragma unroll
        for (int cix = 0; cix < 16; ++cix) {
            p0 += w[cix]      * hv[cix];
            p1 += w[16 + cix] * hv[cix];
            p2 += w[32 + cix] * hv[cix];
            p3 += w[48 + cix] * hv[cix];
        }

        // sum across the 16 k-slices: 4 DPP rounds, all lanes get the sum
        p0 = dpp_add<0xB1>(p0);  p1 = dpp_add<0xB1>(p1);
        p2 = dpp_add<0xB1>(p2);  p3 = dpp_add<0xB1>(p3);
        p0 = dpp_add<0x4E>(p0);  p1 = dpp_add<0x4E>(p1);
        p2 = dpp_add<0x4E>(p2);  p3 = dpp_add<0x4E>(p3);
        p0 = dpp_add<0x141>(p0); p1 = dpp_add<0x141>(p1);
        p2 = dpp_add<0x141>(p2); p3 = dpp_add<0x141>(p3);
        p0 = dpp_add<0x140>(p0); p1 = dpp_add<0x140>(p1);
        p2 = dpp_add<0x140>(p2); p3 = dpp_add<0x140>(p3);

        // all lanes compute activation redundantly (same inputs everywhere);
        // s==0 publishes, s==1 stores h_out in parallel.
        float iv = sigmoidf_(gin0 + p0);
        float fv = sigmoidf_(gin1 + p1);
        float gv = tanh_fast(gin2 + p2);
        float ov = sigmoidf_(gin3 + p3);
        c = fv * c + iv * gv;
        float h = ov * tanh_fast(c);

        if (s == 0) {
            u64 pck = ((u64)(unsigned)(t + 2) << 32) | (u64)__float_as_uint(h);
            u64* fp = msgf + (size_t)(((t + 1) & 1) * 2 + dir) * 256 + j;
            asm volatile("global_store_dwordx2 %0, %1, off sc0"
                         :: "v"((u64)(uintptr_t)fp), "v"(pck) : "memory");
            __hip_atomic_store(&msg[(((t + 1) & 1) * 2 + dir) * 256 + j], pck,
                               __ATOMIC_RELAXED, __HIP_MEMORY_SCOPE_AGENT);
        }
        if (s == 1) h_out[(size_t)tf * 512 + dir * HH + j] = h;

        gin0 = ng0; gin1 = ng1; gin2 = ng2; gin3 = ng3;
        gp = gn;
    }
}

// ---------------------------------------------------------------------------
// Kernel 3: feats[t][k] = dot(h_out[t,:], W_out[k,:]) + b_out[k]  (unchanged)
// ---------------------------------------------------------------------------
__global__ __launch_bounds__(64) void feats_kernel(
    const float* __restrict__ h_out, const float* __restrict__ W_out,
    const float* __restrict__ b_out, float* __restrict__ feats)
{
    const int t = blockIdx.x;
    const int lane = threadIdx.x;
    const int k = lane >> 1, half = lane & 1;
    const float4* hv = (const float4*)(h_out + (size_t)t * 512 + half * 256);
    const float4* wv = (const float4*)(W_out + (size_t)k * 512 + half * 256);
    float p = 0.f;
    #pragma unroll 16
    for (int i = 0; i < 64; ++i) {
        float4 a = hv[i], b = wv[i];
        p += a.x*b.x + a.y*b.y + a.z*b.z + a.w*b.w;
    }
    p += __shfl_xor(p, 1);
    if (half == 0) feats[t * 32 + k] = p + b_out[k];
}

// ---------------------------------------------------------------------------
// Kernel 4: Viterbi. R7: replace the 16 serial __shfl gathers per t (ds pipe,
// ~the dominant per-t cost) with one LDS alpha broadcast: ih==0 lanes write
// the 32 alphas (1 ds_write_b32), every lane reads its 16 via 4 ds_read_b128
// (2 distinct addrs/instr -> broadcast, conflict-free). Single wave => LDS
// pipe is in-order, no barrier needed. obs folded AFTER the max (argmax
// invariant under +obs[j]).
// ---------------------------------------------------------------------------
#define VT_CHUNK 128
__global__ __launch_bounds__(64) void viterbi_kernel(
    const float* __restrict__ feats, const float* __restrict__ trans,
    float* __restrict__ out)
{
    extern __shared__ unsigned char dynls[];
    unsigned char* ixs = dynls;                       // (T-1)*32 = 131040 B
    float* fchunk = (float*)(dynls + 131072);         // VT_CHUNK*32 floats
    __shared__ __align__(16) float alf[32];
    __shared__ float fin[32];

    const int lane = threadIdx.x;
    const int j = lane >> 1, ih = lane & 1;

    float ttr[16];
    #pragma unroll
    for (int q = 0; q < 16; ++q) ttr[q] = trans[(ih * 16 + q) * 32 + j];

    float alpha = 0.f;

    for (int cs = 0; cs < T_LEN; cs += VT_CHUNK) {
        const float4* src = (const float4*)(feats + (size_t)cs * 32);
        float4* dst = (float4*)fchunk;
        #pragma unroll
        for (int i = 0; i < 16; ++i) dst[lane + 64 * i] = src[lane + 64 * i];
        __syncthreads();

        int tbeg = cs;
        if (cs == 0) { alpha = fchunk[j]; tbeg = 1; }

        for (int t = tbeg; t < cs + VT_CHUNK; ++t) {
            if (ih == 0) alf[j] = alpha;   // in-order LDS pipe: safe pre-read
            float obs = fchunk[(t - cs) * 32 + j];
            float4 a0 = *(const float4*)&alf[ih * 16 + 0];
            float4 a1 = *(const float4*)&alf[ih * 16 + 4];
            float4 a2 = *(const float4*)&alf[ih * 16 + 8];
            float4 a3 = *(const float4*)&alf[ih * 16 + 12];

            float v[16]; int ix[16];
            v[0]  = a0.x + ttr[0];  v[1]  = a0.y + ttr[1];
            v[2]  = a0.z + ttr[2];  v[3]  = a0.w + ttr[3];
            v[4]  = a1.x + ttr[4];  v[5]  = a1.y + ttr[5];
            v[6]  = a1.z + ttr[6];  v[7]  = a1.w + ttr[7];
            v[8]  = a2.x + ttr[8];  v[9]  = a2.y + ttr[9];
            v[10] = a2.z + ttr[10]; v[11] = a2.w + ttr[11];
            v[12] = a3.x + ttr[12]; v[13] = a3.y + ttr[13];
            v[14] = a3.z + ttr[14]; v[15] = a3.w + ttr[15];
            #pragma unroll
            for (int q = 0; q < 16; ++q) ix[q] = ih * 16 + q;

            #pragma unroll
            for (int st = 8; st >= 1; st >>= 1)
                #pragma unroll
                for (int q = 0; q < 8; ++q)
                    if (q < st && v[q + st] > v[q]) { v[q] = v[q + st]; ix[q] = ix[q + st]; }
            float best = v[0]; int barg = ix[0];

            float ob = __shfl_xor(best, 1); int oa = __shfl_xor(barg, 1);
            float m0 = ih ? ob : best; int a0i = ih ? oa : barg;
            float m1 = ih ? best : ob; int a1i = ih ? barg : oa;
            float m = m0; int a = a0i;
            if (m1 > m0) { m = m1; a = a1i; }
            if (ih == 0) ixs[(t - 1) * 32 + j] = (unsigned char)a;
            alpha = m + obs;
        }
        __syncthreads();
    }

    if (ih == 0) fin[j] = alpha;
    __syncthreads();

    if (lane == 0) {
        float sc = fin[0]; int cur = 0;
        for (int q = 1; q < 32; ++q)
            if (fin[q] > sc) { sc = fin[q]; cur = q; }
        out[T_LEN] = sc;
        out[T_LEN - 1] = (float)cur;
        for (int t = T_LEN - 2; t >= 0; --t) {
            cur = ixs[t * 32 + cur];
            out[t] = (float)cur;
        }
    }
}

// ---------------------------------------------------------------------------
extern "C" void kernel_launch(void* const* d_in, const int* in_sizes, int n_in,
                              void* d_out, int out_size, void* d_ws, size_t ws_size,
                              hipStream_t stream) {
    const int*   sent  = (const int*)d_in[0];
    const float* embed = (const float*)d_in[1];
    const float* Wih_f = (const float*)d_in[2];
    const float* Whh_f = (const float*)d_in[3];
    const float* bih_f = (const float*)d_in[4];
    const float* bhh_f = (const float*)d_in[5];
    const float* Wih_b = (const float*)d_in[6];
    const float* Whh_b = (const float*)d_in[7];
    const float* bih_b = (const float*)d_in[8];
    const float* bhh_b = (const float*)d_in[9];
    const float* h0    = (const float*)d_in[10];
    const float* c0    = (const float*)d_in[11];
    const float* W_out = (const float*)d_in[12];
    const float* b_out = (const float*)d_in[13];
    const float* trans = (const float*)d_in[14];
    float* out = (float*)d_out;

    float* gates_f = (float*)d_ws;                              // T*1024
    float* gates_b = gates_f + (size_t)T_LEN * 1024;            // T*1024
    float* h_out   = gates_b + (size_t)T_LEN * 1024;            // T*512
    float* feats   = h_out   + (size_t)T_LEN * 512;             // T*32
    u64*   msg     = (u64*)(feats + (size_t)T_LEN * 32);        // 2*2*256 (mirror)
    u64*   msgf    = msg + 1024;                                // 2*2*256 (fast)

    dim3 gproj(T_LEN / 16, 2);
    proj_kernel<<<gproj, 256, 0, stream>>>(sent, embed,
        Wih_f, bih_f, bhh_f, Wih_b, bih_b, bhh_b, gates_f, gates_b);

    lstm_kernel<<<64, 512, 0, stream>>>(Whh_f, Whh_b, gates_f, gates_b,
                                        h0, c0, h_out, msg, msgf);

    feats_kernel<<<T_LEN, 64, 0, stream>>>(h_out, W_out, b_out, feats);

    hipFuncSetAttribute((const void*)viterbi_kernel,
                        hipFuncAttributeMaxDynamicSharedMemorySize, 147456);
    viterbi_kernel<<<1, 64, 147456, stream>>>(feats, trans, out);
}

// Round 4
// 5915.896 us; speedup vs baseline: 4.2207x; 4.2207x over previous
//
#include <hip/hip_runtime.h>
#include <stdint.h>

#define T_LEN 4096
#define E_DIM 256
#define HH 256

typedef unsigned long long u64;

__device__ __forceinline__ float sigmoidf_(float x) {
    // 1/(1+e^-x) with approx rcp (rel err ~1e-7, fine vs 2% score threshold)
    return __builtin_amdgcn_rcpf(1.0f + __expf(-x));
}
// tanh via exp identity; exact saturation at +-1
__device__ __forceinline__ float tanh_fast(float x) {
    float e = __expf(2.0f * x);
    return 1.0f - 2.0f * __builtin_amdgcn_rcpf(e + 1.0f);
}

// DPP-based add of a permuted lane: pure VALU. CTRL: 0xB1 = quad_perm xor1,
// 0x4E = quad_perm xor2, 0x141 = ROW_HALF_MIRROR (l^7), 0x140 = ROW_MIRROR
// (l^15). After the 4-round chain ALL 16 lanes of each 16-row hold the row
// sum (mirrors are valid because values are quad/octet-uniform by then).
template <int CTRL>
__device__ __forceinline__ float dpp_add(float x) {
    int t = __builtin_amdgcn_update_dpp(0, __float_as_int(x), CTRL, 0xF, 0xF, true);
    return x + __int_as_float(t);
}

// ---------------------------------------------------------------------------
// Kernel 1: embedding gather fused with input projection. (unchanged)
// ---------------------------------------------------------------------------
__global__ __launch_bounds__(256) void proj_kernel(
    const int* __restrict__ sent, const float* __restrict__ embed,
    const float* __restrict__ Wih_f, const float* __restrict__ bih_f, const float* __restrict__ bhh_f,
    const float* __restrict__ Wih_b, const float* __restrict__ bih_b, const float* __restrict__ bhh_b,
    float* __restrict__ gates_f, float* __restrict__ gates_b)
{
    __shared__ float4 xt[16][64];   // 16 timesteps x 256 floats
    const int tid = threadIdx.x;
    const int dir = blockIdx.y;
    const int t0  = blockIdx.x * 16;

    const float* Wih = dir ? Wih_b : Wih_f;
    const float* bih = dir ? bih_b : bih_f;
    const float* bhh = dir ? bhh_b : bhh_f;
    float* gates     = dir ? gates_b : gates_f;

    {   // gather 16 embedding rows into LDS (coalesced 16B/lane)
        int row = tid >> 4;
        int c   = tid & 15;
        const float4* src = (const float4*)(embed + (size_t)sent[t0 + row] * E_DIM);
        xt[row][c]      = src[c];
        xt[row][c + 16] = src[c + 16];
        xt[row][c + 32] = src[c + 32];
        xt[row][c + 48] = src[c + 48];
    }
    __syncthreads();

    float acc[4][16];
    #pragma unroll
    for (int ri = 0; ri < 4; ++ri)
        #pragma unroll
        for (int tt = 0; tt < 16; ++tt) acc[ri][tt] = 0.f;

    const float4* wrow0 = (const float4*)(Wih + (size_t)(0 * 256 + tid) * 256);
    const float4* wrow1 = (const float4*)(Wih + (size_t)(1 * 256 + tid) * 256);
    const float4* wrow2 = (const float4*)(Wih + (size_t)(2 * 256 + tid) * 256);
    const float4* wrow3 = (const float4*)(Wih + (size_t)(3 * 256 + tid) * 256);

    for (int k4 = 0; k4 < 64; ++k4) {
        float4 xv[16];
        #pragma unroll
        for (int tt = 0; tt < 16; ++tt) xv[tt] = xt[tt][k4];
        float4 w0 = wrow0[k4], w1 = wrow1[k4], w2 = wrow2[k4], w3 = wrow3[k4];
        #pragma unroll
        for (int tt = 0; tt < 16; ++tt) {
            acc[0][tt] += w0.x*xv[tt].x + w0.y*xv[tt].y + w0.z*xv[tt].z + w0.w*xv[tt].w;
            acc[1][tt] += w1.x*xv[tt].x + w1.y*xv[tt].y + w1.z*xv[tt].z + w1.w*xv[tt].w;
            acc[2][tt] += w2.x*xv[tt].x + w2.y*xv[tt].y + w2.z*xv[tt].z + w2.w*xv[tt].w;
            acc[3][tt] += w3.x*xv[tt].x + w3.y*xv[tt].y + w3.z*xv[tt].z + w3.w*xv[tt].w;
        }
    }

    #pragma unroll
    for (int ri = 0; ri < 4; ++ri) {
        int r = ri * 256 + tid;
        float b = bih[r] + bhh[r];
        #pragma unroll
        for (int tt = 0; tt < 16; ++tt)
            gates[(size_t)(t0 + tt) * 1024 + r] = acc[ri][tt] + b;
    }
}

// ---------------------------------------------------------------------------
// Kernel 2: BiLSTM recurrence. R8 = R6 structure restored verbatim (proven
// 4170us; R7's direct-poll experiment regressed 5.9x -- sc0 loads are not
// coherent and the 8-load sweep congested the XCD L2. Lesson: one slot per
// poller, coherence via compiler atomics only).
// 64 blocks; blockIdx&7 in {0,1} work (dir=xcd). 8 blocks/dir x 32 hidden.
// Thread (j=tid>>4, s=tid&15). Weights AGPR-pinned ("+a", R6-proven: VALU
// reads a-regs in place). h staged via LDS by 224 pollers (1 slot each,
// agent-scope atomic), b64 reads with rotation f(s)=(s+(s>>3))&7 -> 0
// conflicts (R6-measured). DPP reduce leaves the sum in ALL 16 s-lanes.
// R8 delta: lanes s<=1 compute the activation redundantly; s==0 publishes
// msg + h_lds, s==1 stores h_out in parallel (off the publisher's tail).
// ---------------------------------------------------------------------------
__global__ __launch_bounds__(512, 1) void lstm_kernel(
    const float* __restrict__ Whh_f, const float* __restrict__ Whh_b,
    const float* __restrict__ gates_f, const float* __restrict__ gates_b,
    const float* __restrict__ h0, const float* __restrict__ c0,
    float* __restrict__ h_out, u64* __restrict__ msg)
{
    const int xcd  = blockIdx.x & 7;
    const int slot = blockIdx.x >> 3;
    if (xcd > 1) return;               // filler blocks exit
    const int dir = xcd;
    const int g   = slot;              // 0..7, owns hidden [g*32, g*32+32)

    const int tid = threadIdx.x;
    const int jl  = tid >> 4;          // local hidden 0..31
    const int s   = tid & 15;          // k-slice 0..15 (16 floats each)
    const int j   = g * 32 + jl;       // global hidden index
    const int f   = (s + (s >> 3)) & 7;  // bank de-correlation rotation

    const float* Whh   = dir ? Whh_b : Whh_f;
    const float* gates = dir ? gates_b : gates_f;

    // w[gg*16 + i*2 + c] = Whh[gg*256+j][s*16 + ((3i+f)&7)*2 + c]
    // (stored in ds-visit order so the dot loop reads w linearly)
    float w[64];
    #pragma unroll
    for (int gg = 0; gg < 4; ++gg) {
        const float2* row2 = (const float2*)(Whh + (size_t)(gg * 256 + j) * 256 + s * 16);
        #pragma unroll
        for (int i = 0; i < 8; ++i) {
            float2 v = row2[(3 * i + f) & 7];
            w[gg * 16 + i * 2 + 0] = v.x;
            w[gg * 16 + i * 2 + 1] = v.y;
        }
    }
    // AGPR pin: forces w into the accumulator file; VALU reads a-regs as
    // FMA sources in place (gfx90a+), so no per-step accvgpr_read fills and
    // no rematerialization-from-memory.
    #pragma unroll
    for (int k = 0; k < 64; ++k)
        asm volatile("" : "+a"(w[k]));

    // per-i LDS byte offsets (t-invariant; 8 VGPRs, static-indexed)
    int off[8];
    #pragma unroll
    for (int i = 0; i < 8; ++i)
        off[i] = s * 64 + ((3 * i + f) & 7) * 8;

    __shared__ __align__(16) float h_lds[2][256];

    float c = 0.f;
    if (tid < 32) {
        int j0 = g * 32 + tid;
        float h = h0[dir * HH + j0];
        h_lds[0][j0] = h;
        u64 p = ((u64)1u << 32) | (u64)__float_as_uint(h);
        __hip_atomic_store(&msg[(0 * 2 + dir) * 256 + j0], p,
                           __ATOMIC_RELAXED, __HIP_MEMORY_SCOPE_AGENT);
    }
    if (s <= 1) c = c0[dir * HH + j];

    // gin double-buffer: loads for step t issued during step t-1, so the
    // HBM-miss latency (~900 cy) hides under a full step, not just the poll.
    float gin0 = 0.f, gin1 = 0.f, gin2 = 0.f, gin3 = 0.f;
    if (s <= 1) {
        const int tf0 = dir ? (T_LEN - 1) : 0;
        const float* gp = gates + (size_t)tf0 * 1024 + j;
        gin0 = gp[0]; gin1 = gp[256]; gin2 = gp[512]; gin3 = gp[768];
    }

    for (int t = 0; t < T_LEN; ++t) {
        const int tf = dir ? (T_LEN - 1 - t) : t;

        // prefetch NEXT step's gate inputs (consumed at the end of step t+1)
        float ng0 = 0.f, ng1 = 0.f, ng2 = 0.f, ng3 = 0.f;
        if (s <= 1 && t + 1 < T_LEN) {
            const int tfn = dir ? (T_LEN - 2 - t) : (t + 1);
            const float* gp = gates + (size_t)tfn * 1024 + j;
            ng0 = gp[0]; ng1 = gp[256]; ng2 = gp[512]; ng3 = gp[768];
        }

        // poll the 224 remote h values (own 32 written locally last step).
        if (tid < 256 && (tid >> 5) != g) {
            u64* sp = &msg[((t & 1) * 2 + dir) * 256 + tid];
            const unsigned want = (unsigned)(t + 1);
            u64 m;
            do {
                m = __hip_atomic_load(sp, __ATOMIC_RELAXED, __HIP_MEMORY_SCOPE_AGENT);
            } while ((unsigned)(m >> 32) != want);
            h_lds[t & 1][tid] = __uint_as_float((unsigned)m);
        }
        __syncthreads();   // the ONLY barrier per step

        // 4-gate partial dot over this thread's 16-k slice (b64, 0-conflict)
        const char* hb = (const char*)(&h_lds[t & 1][0]);
        float p0 = 0.f, p1 = 0.f, p2 = 0.f, p3 = 0.f;
        #pragma unroll
        for (int i = 0; i < 8; ++i) {
            float2 h2 = *(const float2*)(hb + off[i]);
            p0 += w[i*2+0]*h2.x + w[i*2+1]*h2.y;
            p1 += w[16+i*2+0]*h2.x + w[16+i*2+1]*h2.y;
            p2 += w[32+i*2+0]*h2.x + w[32+i*2+1]*h2.y;
            p3 += w[48+i*2+0]*h2.x + w[48+i*2+1]*h2.y;
        }

        // sum across the 16 k-slices: 4 DPP rounds, all lanes get the sum
        p0 = dpp_add<0xB1>(p0);  p1 = dpp_add<0xB1>(p1);
        p2 = dpp_add<0xB1>(p2);  p3 = dpp_add<0xB1>(p3);
        p0 = dpp_add<0x4E>(p0);  p1 = dpp_add<0x4E>(p1);
        p2 = dpp_add<0x4E>(p2);  p3 = dpp_add<0x4E>(p3);
        p0 = dpp_add<0x141>(p0); p1 = dpp_add<0x141>(p1);
        p2 = dpp_add<0x141>(p2); p3 = dpp_add<0x141>(p3);
        p0 = dpp_add<0x140>(p0); p1 = dpp_add<0x140>(p1);
        p2 = dpp_add<0x140>(p2); p3 = dpp_add<0x140>(p3);

        if (s <= 1) {
            float iv = sigmoidf_(gin0 + p0);
            float fv = sigmoidf_(gin1 + p1);
            float gv = tanh_fast(gin2 + p2);
            float ov = sigmoidf_(gin3 + p3);
            c = fv * c + iv * gv;
            float h = ov * tanh_fast(c);
            if (s == 0) {
                // publish: msg first (critical path), then local LDS
                u64 pck = ((u64)(unsigned)(t + 2) << 32) | (u64)__float_as_uint(h);
                __hip_atomic_store(&msg[(((t + 1) & 1) * 2 + dir) * 256 + j], pck,
                                   __ATOMIC_RELAXED, __HIP_MEMORY_SCOPE_AGENT);
                h_lds[(t + 1) & 1][j] = h;
            } else {
                h_out[(size_t)tf * 512 + dir * HH + j] = h;
            }
        }
        gin0 = ng0; gin1 = ng1; gin2 = ng2; gin3 = ng3;
        // ABA-safe (unchanged protocol): producer overwrites buf (t+1)&1 (its
        // tag-t slot) only after this step's poll saw remote tags t+1, which
        // imply every remote block passed its step-(t-1) barrier and thus
        // consumed tag t already.
    }
}

// ---------------------------------------------------------------------------
// Kernel 3: feats[t][k] = dot(h_out[t,:], W_out[k,:]) + b_out[k]  (unchanged)
// ---------------------------------------------------------------------------
__global__ __launch_bounds__(64) void feats_kernel(
    const float* __restrict__ h_out, const float* __restrict__ W_out,
    const float* __restrict__ b_out, float* __restrict__ feats)
{
    const int t = blockIdx.x;
    const int lane = threadIdx.x;
    const int k = lane >> 1, half = lane & 1;
    const float4* hv = (const float4*)(h_out + (size_t)t * 512 + half * 256);
    const float4* wv = (const float4*)(W_out + (size_t)k * 512 + half * 256);
    float p = 0.f;
    #pragma unroll 16
    for (int i = 0; i < 64; ++i) {
        float4 a = hv[i], b = wv[i];
        p += a.x*b.x + a.y*b.y + a.z*b.z + a.w*b.w;
    }
    p += __shfl_xor(p, 1);
    if (half == 0) feats[t * 32 + k] = p + b_out[k];
}

// ---------------------------------------------------------------------------
// Kernel 4: Viterbi (R7 version, proven: cut ~1.85ms vs the shfl-gather
// version). LDS alpha broadcast: ih==0 lanes write 32 alphas (1 ds_write),
// every lane reads its 16 via 4 ds_read_b128 (2 distinct addrs/instr ->
// broadcast, conflict-free). Single wave => in-order LDS pipe, no barrier.
// obs folded AFTER the max (argmax invariant under +obs[j]).
// ---------------------------------------------------------------------------
#define VT_CHUNK 128
__global__ __launch_bounds__(64) void viterbi_kernel(
    const float* __restrict__ feats, const float* __restrict__ trans,
    float* __restrict__ out)
{
    extern __shared__ unsigned char dynls[];
    unsigned char* ixs = dynls;                       // (T-1)*32 = 131040 B
    float* fchunk = (float*)(dynls + 131072);         // VT_CHUNK*32 floats
    __shared__ __align__(16) float alf[32];
    __shared__ float fin[32];

    const int lane = threadIdx.x;
    const int j = lane >> 1, ih = lane & 1;

    float ttr[16];
    #pragma unroll
    for (int q = 0; q < 16; ++q) ttr[q] = trans[(ih * 16 + q) * 32 + j];

    float alpha = 0.f;

    for (int cs = 0; cs < T_LEN; cs += VT_CHUNK) {
        const float4* src = (const float4*)(feats + (size_t)cs * 32);
        float4* dst = (float4*)fchunk;
        #pragma unroll
        for (int i = 0; i < 16; ++i) dst[lane + 64 * i] = src[lane + 64 * i];
        __syncthreads();

        int tbeg = cs;
        if (cs == 0) { alpha = fchunk[j]; tbeg = 1; }

        for (int t = tbeg; t < cs + VT_CHUNK; ++t) {
            if (ih == 0) alf[j] = alpha;   // in-order LDS pipe: safe pre-read
            float obs = fchunk[(t - cs) * 32 + j];
            float4 a0 = *(const float4*)&alf[ih * 16 + 0];
            float4 a1 = *(const float4*)&alf[ih * 16 + 4];
            float4 a2 = *(const float4*)&alf[ih * 16 + 8];
            float4 a3 = *(const float4*)&alf[ih * 16 + 12];

            float v[16]; int ix[16];
            v[0]  = a0.x + ttr[0];  v[1]  = a0.y + ttr[1];
            v[2]  = a0.z + ttr[2];  v[3]  = a0.w + ttr[3];
            v[4]  = a1.x + ttr[4];  v[5]  = a1.y + ttr[5];
            v[6]  = a1.z + ttr[6];  v[7]  = a1.w + ttr[7];
            v[8]  = a2.x + ttr[8];  v[9]  = a2.y + ttr[9];
            v[10] = a2.z + ttr[10]; v[11] = a2.w + ttr[11];
            v[12] = a3.x + ttr[12]; v[13] = a3.y + ttr[13];
            v[14] = a3.z + ttr[14]; v[15] = a3.w + ttr[15];
            #pragma unroll
            for (int q = 0; q < 16; ++q) ix[q] = ih * 16 + q;

            #pragma unroll
            for (int st = 8; st >= 1; st >>= 1)
                #pragma unroll
                for (int q = 0; q < 8; ++q)
                    if (q < st && v[q + st] > v[q]) { v[q] = v[q + st]; ix[q] = ix[q + st]; }
            float best = v[0]; int barg = ix[0];

            float ob = __shfl_xor(best, 1); int oa = __shfl_xor(barg, 1);
            float m0 = ih ? ob : best; int a0i = ih ? oa : barg;
            float m1 = ih ? best : ob; int a1i = ih ? barg : oa;
            float m = m0; int a = a0i;
            if (m1 > m0) { m = m1; a = a1i; }
            if (ih == 0) ixs[(t - 1) * 32 + j] = (unsigned char)a;
            alpha = m + obs;
        }
        __syncthreads();
    }

    if (ih == 0) fin[j] = alpha;
    __syncthreads();

    if (lane == 0) {
        float sc = fin[0]; int cur = 0;
        for (int q = 1; q < 32; ++q)
            if (fin[q] > sc) { sc = fin[q]; cur = q; }
        out[T_LEN] = sc;
        out[T_LEN - 1] = (float)cur;
        for (int t = T_LEN - 2; t >= 0; --t) {
            cur = ixs[t * 32 + cur];
            out[t] = (float)cur;
        }
    }
}

// ---------------------------------------------------------------------------
extern "C" void kernel_launch(void* const* d_in, const int* in_sizes, int n_in,
                              void* d_out, int out_size, void* d_ws, size_t ws_size,
                              hipStream_t stream) {
    const int*   sent  = (const int*)d_in[0];
    const float* embed = (const float*)d_in[1];
    const float* Wih_f = (const float*)d_in[2];
    const float* Whh_f = (const float*)d_in[3];
    const float* bih_f = (const float*)d_in[4];
    const float* bhh_f = (const float*)d_in[5];
    const float* Wih_b = (const float*)d_in[6];
    const float* Whh_b = (const float*)d_in[7];
    const float* bih_b = (const float*)d_in[8];
    const float* bhh_b = (const float*)d_in[9];
    const float* h0    = (const float*)d_in[10];
    const float* c0    = (const float*)d_in[11];
    const float* W_out = (const float*)d_in[12];
    const float* b_out = (const float*)d_in[13];
    const float* trans = (const float*)d_in[14];
    float* out = (float*)d_out;

    float* gates_f = (float*)d_ws;                              // T*1024
    float* gates_b = gates_f + (size_t)T_LEN * 1024;            // T*1024
    float* h_out   = gates_b + (size_t)T_LEN * 1024;            // T*512
    float* feats   = h_out   + (size_t)T_LEN * 512;             // T*32
    u64*   msg     = (u64*)(feats + (size_t)T_LEN * 32);        // 2*2*256

    dim3 gproj(T_LEN / 16, 2);
    proj_kernel<<<gproj, 256, 0, stream>>>(sent, embed,
        Wih_f, bih_f, bhh_f, Wih_b, bih_b, bhh_b, gates_f, gates_b);

    lstm_kernel<<<64, 512, 0, stream>>>(Whh_f, Whh_b, gates_f, gates_b,
                                        h0, c0, h_out, msg);

    feats_kernel<<<T_LEN, 64, 0, stream>>>(h_out, W_out, b_out, feats);

    hipFuncSetAttribute((const void*)viterbi_kernel,
                        hipFuncAttributeMaxDynamicSharedMemorySize, 147456);
    viterbi_kernel<<<1, 64, 147456, stream>>>(feats, trans, out);
}